// Round 5
// baseline (494.371 us; speedup 1.0000x reference)
//
#include <hip/hip_runtime.h>
#include <cstdint>

#define HEADS 4

typedef __attribute__((ext_vector_type(8))) short bf16x8;
typedef __attribute__((ext_vector_type(4))) float floatx4;

__device__ __forceinline__ short f2bf(float f) {
    union { float f; unsigned u; } v; v.f = f;
    unsigned r = v.u + 0x7FFFu + ((v.u >> 16) & 1u);
    return (short)(r >> 16);
}
__device__ __forceinline__ float bflo(unsigned u) {
    union { unsigned u; float f; } v; v.u = u << 16; return v.f;
}
__device__ __forceinline__ float bfhi(unsigned u) {
    union { unsigned u; float f; } v; v.u = u & 0xffff0000u; return v.f;
}
__device__ __forceinline__ float dot2(unsigned a, unsigned b) {
    return bflo(a) * bflo(b) + bfhi(a) * bfhi(b);
}
__device__ __forceinline__ void async16(const void* g, void* l) {
    __builtin_amdgcn_global_load_lds((const __attribute__((address_space(1))) void*)g,
                                     (__attribute__((address_space(3))) void*)l,
                                     16, 0, 0);
}

// ============== skinny-K bf16 MFMA GEMM: B resident in LDS, A direct =========
// A: [.][lda] bf16, rows row0..row0+127 read (buffers padded to Npad).
// Bt: [NC][K] bf16 (B^T). Cb[row][ldc] = relu?(A@B + bias - sub[batch[row]]).
// relu_mode: 0=none, 1=relu, 2=relu only for col0>=128 (combo kernel).
// K-loop has NO barriers: one __syncthreads after one-time B staging.
// Epilogue via wave-private LDS slice (no block barriers), dwordx4 stores.
template<int K, int BN>
__global__ __launch_bounds__(256)
void gemm_rk(const short* __restrict__ A, int lda,
             const short* __restrict__ Bt,
             const float* __restrict__ bias,
             const float* __restrict__ sub, int subld,
             const int* __restrict__ batch,
             short* __restrict__ Cb, int ldc,
             float* __restrict__ bnsum, float* __restrict__ bnsumsq,
             int M, int relu_mode)
{
    constexpr int NI  = BN / 16;      // 16-col n-tiles
    constexpr int KP  = K / 32;       // 32-k panels
    constexpr int BNP = BN + 8;       // padded epilogue stride
    __shared__ short smem[BN * K + 64 * BNP];
    short* Bsm = smem;
    short* Csm = smem + BN * K;

    const int tid  = threadIdx.x;
    const int lane = tid & 63;
    const int wv   = tid >> 6;
    const int lq   = lane >> 4;
    const int lr   = lane & 15;
    const int row0 = blockIdx.x * 128;
    const int col0 = blockIdx.y * BN;
    const int sw   = lq ^ ((lr >> 1) & 3);
    const bool do_relu = (relu_mode == 1) || (relu_mode == 2 && col0 >= 128);

    // ---- one-time B staging (panel-swizzled), async direct-to-LDS ----
    const short* gB = Bt + (size_t)col0 * K;
    constexpr int ROUNDS = (KP * BN * 4) / 256;
#pragma unroll
    for (int rr = 0; rr < ROUNDS; ++rr) {
        int cidb = rr * 256 + wv * 64;          // wave-uniform chunk base
        int cid  = cidb + lane;
        int panel = cid / (BN * 4);
        int rowc  = cid % (BN * 4);
        int row = rowc >> 2, c = rowc & 3;
        int cg  = c ^ ((row >> 1) & 3);
        async16(gB + (size_t)row * K + panel * 32 + cg * 8, &Bsm[(size_t)cidb * 8]);
    }

    // ---- all A fragments: direct global->reg, issued before the barrier ----
    const int rbase = row0 + wv * 32;
    bf16x8 af[KP][2];
#pragma unroll
    for (int kp = 0; kp < KP; ++kp)
#pragma unroll
        for (int mi = 0; mi < 2; ++mi)
            af[kp][mi] = *(const bf16x8*)&A[(size_t)(rbase + mi * 16 + lr) * lda
                                            + kp * 32 + lq * 8];

    __syncthreads();   // the only block barrier

    floatx4 acc[2][NI];
#pragma unroll
    for (int mi = 0; mi < 2; ++mi)
#pragma unroll
        for (int ni = 0; ni < NI; ++ni) acc[mi][ni] = (floatx4)(0.f);

#pragma unroll
    for (int kp = 0; kp < KP; ++kp) {
        bf16x8 bfr[NI];
#pragma unroll
        for (int ni = 0; ni < NI; ++ni)
            bfr[ni] = *(const bf16x8*)&Bsm[((size_t)(kp * BN + ni * 16 + lr) * 4 + sw) * 8];
#pragma unroll
        for (int mi = 0; mi < 2; ++mi)
#pragma unroll
            for (int ni = 0; ni < NI; ++ni)
                acc[mi][ni] = __builtin_amdgcn_mfma_f32_16x16x32_bf16(
                    af[kp][mi], bfr[ni], acc[mi][ni], 0, 0, 0);
    }

    // ---- epilogue: wave-private LDS slice, no block barriers ----
    float bias_v[NI];
#pragma unroll
    for (int ni = 0; ni < NI; ++ni)
        bias_v[ni] = bias ? bias[col0 + ni * 16 + lr] : 0.f;
    float s_acc[NI], ss_acc[NI];
#pragma unroll
    for (int ni = 0; ni < NI; ++ni) { s_acc[ni] = 0.f; ss_acc[ni] = 0.f; }

    short* Cw = Csm + wv * 16 * BNP;
#pragma unroll
    for (int mi = 0; mi < 2; ++mi) {
        __builtin_amdgcn_wave_barrier();
#pragma unroll
        for (int r = 0; r < 4; ++r) {
            int gr = rbase + mi * 16 + lq * 4 + r;
            const float* subrow = nullptr;
            if (sub) {
                int bidx = batch[min(gr, M - 1)];
                subrow = &sub[(size_t)bidx * subld + col0];
            }
#pragma unroll
            for (int ni = 0; ni < NI; ++ni) {
                float v = acc[mi][ni][r] + bias_v[ni];
                if (sub) v -= subrow[ni * 16 + lr];
                if (do_relu) v = fmaxf(v, 0.f);
                if (bnsum && gr < M) {
                    float rv = fmaxf(v, 0.f);
                    s_acc[ni] += rv;
                    ss_acc[ni] = fmaf(rv, rv, ss_acc[ni]);
                }
                Cw[(lq * 4 + r) * BNP + ni * 16 + lr] = f2bf(v);
            }
        }
        __builtin_amdgcn_wave_barrier();
        // readback coalesced + dwordx4 stores (in-order DS pipe per wave)
#pragma unroll
        for (int it = 0; it < BN / 32; ++it) {
            int t  = it * 64 + lane;
            int rl = t / (BN / 8);
            int chk = t % (BN / 8);
            uint4 d = *(const uint4*)&Cw[rl * BNP + chk * 8];
            int gr = rbase + mi * 16 + rl;
            *(uint4*)&Cb[(size_t)gr * ldc + col0 + chk * 8] = d;
        }
        __builtin_amdgcn_wave_barrier();
    }

    if (bnsum) {
#pragma unroll
        for (int ni = 0; ni < NI; ++ni) {
            float sv = s_acc[ni], ssv = ss_acc[ni];
            sv += __shfl_xor(sv, 16); sv += __shfl_xor(sv, 32);
            ssv += __shfl_xor(ssv, 16); ssv += __shfl_xor(ssv, 32);
            if (lq == 0) {
                int gc = col0 + ni * 16 + lr;
                atomicAdd(&bnsum[gc], sv);
                atomicAdd(&bnsumsq[gc], ssv);
            }
        }
    }
}

// ---------------- x fp32 -> bf16 (padded with zeros) -------------------------
__global__ __launch_bounds__(256)
void f32_to_bf16_pad(const float* __restrict__ in, short* __restrict__ out,
                     long n_in, long n_out)
{
    long i4 = ((long)blockIdx.x * 256 + threadIdx.x) * 4;
    if (i4 >= n_out) return;
    float4 v = make_float4(0.f, 0.f, 0.f, 0.f);
    if (i4 < n_in) v = *(const float4*)&in[i4];
    short4 o;
    o.x = f2bf(v.x); o.y = f2bf(v.y); o.z = f2bf(v.z); o.w = f2bf(v.w);
    *(short4*)&out[i4] = o;
}

// ---- attention fold: T[h] = A_h @ W_h^T -------------------------------------
__global__ __launch_bounds__(128)
void att_fold1(const float* __restrict__ A_att, const float* __restrict__ W_att,
               float* __restrict__ T)
{
    int h = blockIdx.y, i = blockIdx.x, j = threadIdx.x;
    const float* A = A_att + (size_t)h * 16384;
    const float* W = W_att + (size_t)h * 16384;
    float s = 0.f;
    for (int k = 0; k < 128; ++k) s = fmaf(A[i * 128 + k], W[j * 128 + k], s);
    T[(size_t)h * 16384 + i * 128 + j] = s;
}

// ---- Bt3 rows 0..127: Mt[n][k] = (sum_h W_h@T_h)[k][n] bf16 -----------------
__global__ __launch_bounds__(128)
void att_fold2(const float* __restrict__ W_att, const float* __restrict__ T,
               short* __restrict__ Bt3)
{
    int i = blockIdx.x, j = threadIdx.x;
    float s = 0.f;
    for (int h = 0; h < HEADS; ++h) {
        const float* W = W_att + (size_t)h * 16384 + i * 128;
        const float* Th = T + (size_t)h * 16384;
        for (int k = 0; k < 128; ++k) s = fmaf(W[k], Th[k * 128 + j], s);
    }
    Bt3[(size_t)j * 128 + i] = f2bf(s);
}

// ---- u = sum W_h(A_h b_h), v = sum (b_h A_h)W_h^T, c0 = sum b_h.(A_h b_h) ---
__global__ __launch_bounds__(128)
void att_fold3(const float* __restrict__ W_att, const float* __restrict__ b_att,
               const float* __restrict__ A_att,
               float* __restrict__ u, float* __restrict__ v, float* __restrict__ c0)
{
    __shared__ float tb[HEADS][128], tv[HEADS][128];
    int t = threadIdx.x;
    for (int h = 0; h < HEADS; ++h) {
        const float* A = A_att + (size_t)h * 16384;
        const float* b = b_att + h * 128;
        float sb = 0.f, sv = 0.f;
        for (int j = 0; j < 128; ++j) {
            sb = fmaf(A[t * 128 + j], b[j], sb);
            sv = fmaf(b[j], A[j * 128 + t], sv);
        }
        tb[h][t] = sb; tv[h][t] = sv;
    }
    __syncthreads();
    float su = 0.f, sv2 = 0.f;
    for (int h = 0; h < HEADS; ++h) {
        const float* W = W_att + (size_t)h * 16384 + t * 128;
        for (int k = 0; k < 128; ++k) {
            su = fmaf(W[k], tb[h][k], su);
            sv2 = fmaf(W[k], tv[h][k], sv2);
        }
    }
    u[t] = su; v[t] = sv2;
    if (t == 0) {
        float c = 0.f;
        for (int h = 0; h < HEADS; ++h)
            for (int k = 0; k < 128; ++k) c += b_att[h * 128 + k] * tb[h][k];
        *c0 = c;
    }
}

// ---- per-node a = x.u, b = x.v ----------------------------------------------
__global__ __launch_bounds__(256)
void node_ab(const float* __restrict__ x, const float* __restrict__ u,
             const float* __restrict__ v, float* __restrict__ a,
             float* __restrict__ b, int N)
{
    int t = blockIdx.x * 256 + threadIdx.x;
    int n = t >> 4, j = t & 15;
    if (n >= N) return;
    const float* xr = x + (size_t)n * 128 + j * 8;
    float4 x0 = *(const float4*)xr;
    float4 x1 = *(const float4*)(xr + 4);
    const float* up = u + j * 8;
    const float* vp = v + j * 8;
    float sa = x0.x*up[0] + x0.y*up[1] + x0.z*up[2] + x0.w*up[3]
             + x1.x*up[4] + x1.y*up[5] + x1.z*up[6] + x1.w*up[7];
    float sb = x0.x*vp[0] + x0.y*vp[1] + x0.z*vp[2] + x0.w*vp[3]
             + x1.x*vp[4] + x1.y*vp[5] + x1.z*vp[6] + x1.w*vp[7];
    sa += __shfl_xor(sa, 1); sa += __shfl_xor(sa, 2);
    sa += __shfl_xor(sa, 4); sa += __shfl_xor(sa, 8);
    sb += __shfl_xor(sb, 1); sb += __shfl_xor(sb, 2);
    sb += __shfl_xor(sb, 4); sb += __shfl_xor(sb, 8);
    if (j == 0) { a[n] = sa; b[n] = sb; }
}

// ---- edge attention: sigmoid(0.25*(q[r].x[c] + a[r] + b[c] + c0)) -----------
__global__ __launch_bounds__(256)
void edge_att(const short* __restrict__ xh, const short* __restrict__ xb,
              const int* __restrict__ row, const int* __restrict__ col,
              const float* __restrict__ a, const float* __restrict__ b,
              const float* __restrict__ c0, float* __restrict__ att, int E)
{
    int t = blockIdx.x * 256 + threadIdx.x;
    int e = t >> 4, j = t & 15;
    if (e >= E) return;
    int r = row[e], c = col[e];
    uint4 qa = *(const uint4*)&xh[(size_t)r * 384 + j * 8];   // q part of combo
    uint4 xa = *(const uint4*)&xb[(size_t)c * 128 + j * 8];
    float p = dot2(qa.x, xa.x) + dot2(qa.y, xa.y) + dot2(qa.z, xa.z) + dot2(qa.w, xa.w);
    p += __shfl_xor(p, 1); p += __shfl_xor(p, 2);
    p += __shfl_xor(p, 4); p += __shfl_xor(p, 8);
    if (j == 0) {
        float s = 0.25f * (p + a[r] + b[c] + *c0);
        att[e] = 1.f / (1.f + expf(-s));
    }
}

// --------- Bt3 rows 128..383: W_f1^T bf16 ------------------------------------
__global__ __launch_bounds__(256)
void wf1_transpose(const float* __restrict__ W, short* __restrict__ Bt3)
{
    int r = blockIdx.x;    // 0..127
    int c = threadIdx.x;   // 0..255
    Bt3[(size_t)(128 + c) * 128 + r] = f2bf(W[(size_t)r * 256 + c]);
}

// --------- bias3 = [0 x128 | b_f1] -------------------------------------------
__global__ __launch_bounds__(128)
void build_bias3(const float* __restrict__ b_f1, float* __restrict__ bias3)
{
    int j = blockIdx.x * 128 + threadIdx.x;   // 0..383
    bias3[j] = (j < 128) ? 0.f : b_f1[j - 128];
}

// --------- G1 (64x64) -> G1t bf16; G2 (64x128) -> G2t[128][64] bf16 ----------
__global__ __launch_bounds__(64)
void transpose_g(const float* __restrict__ G1, const float* __restrict__ G2,
                 short* __restrict__ G1t, short* __restrict__ G2t)
{
    int b = blockIdx.x;
    int j = threadIdx.x;
    if (b < 64) {
        G1t[(size_t)j * 64 + b] = f2bf(G1[(size_t)b * 64 + j]);
    } else {
        int n = b - 64;
        G2t[(size_t)n * 64 + j] = f2bf(G2[(size_t)j * 128 + n]);
    }
}

// ---- Wefft[o][k] = (W_f2 @ (W_l0[2j]+W_l0[2j+1]))[k][o] bf16; beff fp32 -----
__global__ __launch_bounds__(64)
void build_weff(const float* __restrict__ W_f2, const float* __restrict__ b_f2,
                const float* __restrict__ W_l0, const float* __restrict__ b_l0,
                short* __restrict__ Wefft, float* __restrict__ beff)
{
    int o = threadIdx.x;
    int k = blockIdx.x;
    if (k < 256) {
        float a = 0.f;
        for (int j = 0; j < 8; ++j) {
            float w = W_l0[(2 * j) * 64 + o] + W_l0[(2 * j + 1) * 64 + o];
            a = fmaf(W_f2[k * 8 + j], w, a);
        }
        Wefft[(size_t)o * 256 + k] = f2bf(a);
    } else {
        float a = b_l0[o];
        for (int j = 0; j < 8; ++j) {
            float w = W_l0[(2 * j) * 64 + o] + W_l0[(2 * j + 1) * 64 + o];
            a = fmaf(b_f2[j], w, a);
        }
        beff[o] = a;
    }
}

// -------- segment sums over sorted batch, 64 bf16 features -------------------
__global__ __launch_bounds__(256)
void segmean_bf(const short* __restrict__ v, const int* __restrict__ batch,
                float* __restrict__ sums, float* __restrict__ cnt,
                int N, int do_cnt)
{
    const int lane = threadIdx.x & 63;
    const int wv = threadIdx.x >> 6;
    const int lq = lane >> 4;
    const int lr = lane & 15;
    int start = (blockIdx.x * 4 + wv) * 64;
    if (start >= N) return;
    int end = min(start + 64, N);
    int i = start + lq;
    float4 a = make_float4(0.f, 0.f, 0.f, 0.f);
    float run = 0.f;
    int cur = (i < end) ? batch[i] : -1;
    for (; i < end; i += 4) {
        int g = batch[i];
        if (g != cur) {
            float* s = &sums[(size_t)cur * 64 + lr * 4];
            atomicAdd(&s[0], a.x); atomicAdd(&s[1], a.y);
            atomicAdd(&s[2], a.z); atomicAdd(&s[3], a.w);
            if (do_cnt && lr == 0) atomicAdd(&cnt[cur], run);
            cur = g; a = make_float4(0.f, 0.f, 0.f, 0.f); run = 0.f;
        }
        uint2 d = *(const uint2*)&v[(size_t)i * 64 + lr * 4];
        a.x += bflo(d.x); a.y += bfhi(d.x);
        a.z += bflo(d.y); a.w += bfhi(d.y);
        run += 1.f;
    }
    if (cur >= 0) {
        float* s = &sums[(size_t)cur * 64 + lr * 4];
        atomicAdd(&s[0], a.x); atomicAdd(&s[1], a.y);
        atomicAdd(&s[2], a.z); atomicAdd(&s[3], a.w);
        if (do_cnt && lr == 0) atomicAdd(&cnt[cur], run);
    }
}

__global__ void xm_compute(const float* __restrict__ sums, const float* __restrict__ cnt,
                           const float* __restrict__ L, float* __restrict__ xm, int Fout)
{
    int g = blockIdx.x;
    int j = threadIdx.x;
    float inv = 1.f / fmaxf(cnt[g], 1.f);
    float a = 0.f;
    for (int k = 0; k < 64; ++k)
        a = fmaf(sums[g * 64 + k] * inv, L[k * Fout + j], a);
    xm[g * Fout + j] = a;
}

__global__ __launch_bounds__(128)
void bn_final(const float* __restrict__ bnsum, const float* __restrict__ bnsumsq,
              const float* __restrict__ gamma, const float* __restrict__ beta,
              float* __restrict__ scale, float* __restrict__ shift, float invN)
{
    int f = threadIdx.x;
    float mu = bnsum[f] * invN;
    float var = bnsumsq[f] * invN - mu * mu;
    float sc = gamma[f] * rsqrtf(var + 1e-5f);
    scale[f] = sc;
    shift[f] = beta[f] - mu * sc;
}

// ---------------- out = x + relu(x0_bf)*scale + shift ------------------------
__global__ __launch_bounds__(256)
void finalize(const float* __restrict__ x, const short* __restrict__ x0b,
              const float* __restrict__ scale, const float* __restrict__ shift,
              float* __restrict__ out, int total4)
{
    int i = blockIdx.x * blockDim.x + threadIdx.x;
    if (i >= total4) return;
    int f0 = (i * 4) & 127;
    uint2 h2 = ((const uint2*)x0b)[i];
    float4 xv = ((const float4*)x)[i];
    float4 sc = *(const float4*)&scale[f0];
    float4 sh = *(const float4*)&shift[f0];
    float4 o;
    o.x = xv.x + fmaxf(bflo(h2.x), 0.f) * sc.x + sh.x;
    o.y = xv.y + fmaxf(bfhi(h2.x), 0.f) * sc.y + sh.y;
    o.z = xv.z + fmaxf(bflo(h2.y), 0.f) * sc.z + sh.z;
    o.w = xv.w + fmaxf(bfhi(h2.y), 0.f) * sc.w + sh.w;
    ((float4*)out)[i] = o;
}

extern "C" void kernel_launch(void* const* d_in, const int* in_sizes, int n_in,
                              void* d_out, int out_size, void* d_ws, size_t ws_size,
                              hipStream_t stream)
{
    const float* x      = (const float*)d_in[0];
    const int*   ei     = (const int*)d_in[1];
    const int*   batch  = (const int*)d_in[2];
    const float* W_f1   = (const float*)d_in[3];
    const float* b_f1   = (const float*)d_in[4];
    const float* W_f2   = (const float*)d_in[5];
    const float* b_f2   = (const float*)d_in[6];
    const float* W_l0   = (const float*)d_in[7];
    const float* b_l0   = (const float*)d_in[8];
    const float* G1     = (const float*)d_in[9];
    const float* b_g1   = (const float*)d_in[10];
    const float* L1     = (const float*)d_in[11];
    const float* G2     = (const float*)d_in[12];
    const float* b_g2   = (const float*)d_in[13];
    const float* L2     = (const float*)d_in[14];
    const float* gam    = (const float*)d_in[15];
    const float* bet    = (const float*)d_in[16];
    const float* W_att  = (const float*)d_in[17];
    const float* b_att  = (const float*)d_in[18];
    const float* A_att  = (const float*)d_in[19];

    const int N = in_sizes[2];
    const int E = in_sizes[1] / 2;
    const int Npad = (N + 127) & ~127;

    char* p = (char*)d_ws;
    auto alloc = [&](size_t bytes) {
        char* r = p;
        p += (bytes + 255) & ~(size_t)255;
        return r;
    };

    short* x_bf   = (short*)alloc((size_t)Npad * 128 * 2);
    short* xh     = (short*)alloc((size_t)Npad * 384 * 2);  // [q | hidden]
    short* s0_bf  = (short*)alloc((size_t)Npad * 64 * 2);
    short* s1_bf  = (short*)alloc((size_t)Npad * 64 * 2);
    short* x0_bf  = (short*)alloc((size_t)Npad * 128 * 2);
    float* a_arr  = (float*)alloc((size_t)N * 4);
    float* b_arr  = (float*)alloc((size_t)N * 4);
    float* Tbuf   = (float*)alloc((size_t)HEADS * 128 * 128 * 4);
    short* Bt3    = (short*)alloc(384 * 128 * 2);
    float* bias3  = (float*)alloc(384 * 4);
    float* u_v    = (float*)alloc(128 * 4);
    float* v_v    = (float*)alloc(128 * 4);
    float* c0_v   = (float*)alloc(4);
    short* Wefft  = (short*)alloc(64 * 256 * 2);
    float* beff   = (float*)alloc(64 * 4);
    short* G1t    = (short*)alloc(64 * 64 * 2);
    short* G2t    = (short*)alloc(128 * 64 * 2);
    float* zblk   = (float*)alloc((64 * 64 * 2 + 64 + 256) * 4);
    float* xm1    = (float*)alloc(64 * 64 * 4);
    float* xm2    = (float*)alloc(64 * 128 * 4);
    float* bscale = (float*)alloc(128 * 4);
    float* bshift = (float*)alloc(128 * 4);

    if ((size_t)(p - (char*)d_ws) > ws_size) return;

    float* sums1   = zblk;
    float* sums2   = zblk + 64 * 64;
    float* cnt     = zblk + 64 * 64 * 2;
    float* bnsum   = cnt + 64;
    float* bnsumsq = bnsum + 128;

    float* out0    = (float*)d_out;
    float* att_out = out0 + (size_t)N * 128;

    hipMemsetAsync(zblk, 0, (64 * 64 * 2 + 64 + 256) * 4, stream);

    // prologue: pack x, fold attention, build weights
    {
        long n_in_e = (long)N * 128, n_out_e = (long)Npad * 128;
        long blocks = (n_out_e / 4 + 255) / 256;
        f32_to_bf16_pad<<<(int)blocks, 256, 0, stream>>>(x, x_bf, n_in_e, n_out_e);
    }
    att_fold1<<<dim3(128, HEADS), 128, 0, stream>>>(A_att, W_att, Tbuf);
    att_fold2<<<128, 128, 0, stream>>>(W_att, Tbuf, Bt3);
    att_fold3<<<1, 128, 0, stream>>>(W_att, b_att, A_att, u_v, v_v, c0_v);
    node_ab<<<(N * 16 + 255) / 256, 256, 0, stream>>>(x, u_v, v_v, a_arr, b_arr, N);
    wf1_transpose<<<128, 256, 0, stream>>>(W_f1, Bt3);
    build_bias3<<<3, 128, 0, stream>>>(b_f1, bias3);
    build_weff<<<257, 64, 0, stream>>>(W_f2, b_f2, W_l0, b_l0, Wefft, beff);
    transpose_g<<<192, 64, 0, stream>>>(G1, G2, G1t, G2t);

    const int gmm = Npad / 128;

    // combo: xh = x @ [M | W_f1] (+[0|b_f1], relu on hidden half)
    gemm_rk<128, 128><<<dim3(gmm, 3), 256, 0, stream>>>(
        x_bf, 128, Bt3, bias3, nullptr, 0, nullptr, xh, 384,
        nullptr, nullptr, N, 2);
    edge_att<<<(E * 16 + 255) / 256, 256, 0, stream>>>(
        xh, x_bf, ei, ei + E, a_arr, b_arr, c0_v, att_out, E);

    // s0 = relu(hidden @ W_eff + b_eff)
    gemm_rk<256, 64><<<dim3(gmm, 1), 256, 0, stream>>>(
        xh + 128, 384, Wefft, beff, nullptr, 0, nullptr, s0_bf, 64,
        nullptr, nullptr, N, 1);

    segmean_bf<<<(N + 255) / 256, 256, 0, stream>>>(s0_bf, batch, sums1, cnt, N, 1);
    xm_compute<<<64, 64, 0, stream>>>(sums1, cnt, L1, xm1, 64);
    // s1 = relu(s0 @ G1 + b_g1 - xm1[batch])
    gemm_rk<64, 64><<<dim3(gmm, 1), 256, 0, stream>>>(
        s0_bf, 64, G1t, b_g1, xm1, 64, batch, s1_bf, 64,
        nullptr, nullptr, N, 1);
    segmean_bf<<<(N + 255) / 256, 256, 0, stream>>>(s1_bf, batch, sums2, cnt, N, 0);
    xm_compute<<<64, 128, 0, stream>>>(sums2, cnt, L2, xm2, 128);
    // x0 = s1 @ G2 + b_g2 - xm2[batch]  + fused BN stats
    gemm_rk<64, 128><<<dim3(gmm, 1), 256, 0, stream>>>(
        s1_bf, 64, G2t, b_g2, xm2, 128, batch, x0_bf, 128,
        bnsum, bnsumsq, N, 0);

    bn_final<<<1, 128, 0, stream>>>(bnsum, bnsumsq, gam, bet, bscale, bshift, 1.f / (float)N);
    finalize<<<((N * 128 / 4) + 255) / 256, 256, 0, stream>>>(x, x0_bf, bscale, bshift,
                                                              out0, N * 128 / 4);
}

// Round 6
// 451.924 us; speedup vs baseline: 1.0939x; 1.0939x over previous
//
#include <hip/hip_runtime.h>
#include <cstdint>

#define HEADS 4

typedef __attribute__((ext_vector_type(8))) short bf16x8;
typedef __attribute__((ext_vector_type(4))) float floatx4;

__device__ __forceinline__ short f2bf(float f) {
    union { float f; unsigned u; } v; v.f = f;
    unsigned r = v.u + 0x7FFFu + ((v.u >> 16) & 1u);
    return (short)(r >> 16);
}
__device__ __forceinline__ float bflo(unsigned u) {
    union { unsigned u; float f; } v; v.u = u << 16; return v.f;
}
__device__ __forceinline__ float bfhi(unsigned u) {
    union { unsigned u; float f; } v; v.u = u & 0xffff0000u; return v.f;
}
__device__ __forceinline__ float dot2(unsigned a, unsigned b) {
    return bflo(a) * bflo(b) + bfhi(a) * bfhi(b);
}
__device__ __forceinline__ void async16(const void* g, void* l) {
    __builtin_amdgcn_global_load_lds((const __attribute__((address_space(1))) void*)g,
                                     (__attribute__((address_space(3))) void*)l,
                                     16, 0, 0);
}

// ============== skinny-K bf16 MFMA GEMM: B resident in LDS, A direct =========
// One block barrier total. BN-col epilogue via wave-private LDS + dwordx4.
// bnpart: optional per-block BN-partials (NO atomics): block writes
// bnpart[blockIdx.x*256 + {0..127 sum, 128..255 sumsq}] of relu(C) cols.
template<int K, int BN>
__global__ __launch_bounds__(256)
void gemm_rk(const short* __restrict__ A, int lda,
             const short* __restrict__ Bt,
             const float* __restrict__ bias,
             const float* __restrict__ sub, int subld,
             const int* __restrict__ batch,
             short* __restrict__ Cb, int ldc,
             float* __restrict__ bnpart,
             int M, int do_relu)
{
    constexpr int NI  = BN / 16;
    constexpr int KP  = K / 32;
    constexpr int BNP = BN + 8;
    __shared__ short smem[BN * K + 64 * BNP];
    __shared__ float bnred[4 * 256];
    short* Bsm = smem;
    short* Csm = smem + BN * K;

    const int tid  = threadIdx.x;
    const int lane = tid & 63;
    const int wv   = tid >> 6;
    const int lq   = lane >> 4;
    const int lr   = lane & 15;
    const int row0 = blockIdx.x * 128;
    const int col0 = blockIdx.y * BN;
    const int sw   = lq ^ ((lr >> 1) & 3);

    const short* gB = Bt + (size_t)col0 * K;
    constexpr int ROUNDS = (KP * BN * 4) / 256;
#pragma unroll
    for (int rr = 0; rr < ROUNDS; ++rr) {
        int cidb = rr * 256 + wv * 64;
        int cid  = cidb + lane;
        int panel = cid / (BN * 4);
        int rowc  = cid % (BN * 4);
        int row = rowc >> 2, c = rowc & 3;
        int cg  = c ^ ((row >> 1) & 3);
        async16(gB + (size_t)row * K + panel * 32 + cg * 8, &Bsm[(size_t)cidb * 8]);
    }

    const int rbase = row0 + wv * 32;
    bf16x8 af[KP][2];
#pragma unroll
    for (int kp = 0; kp < KP; ++kp)
#pragma unroll
        for (int mi = 0; mi < 2; ++mi)
            af[kp][mi] = *(const bf16x8*)&A[(size_t)(rbase + mi * 16 + lr) * lda
                                            + kp * 32 + lq * 8];

    __syncthreads();

    floatx4 acc[2][NI];
#pragma unroll
    for (int mi = 0; mi < 2; ++mi)
#pragma unroll
        for (int ni = 0; ni < NI; ++ni) acc[mi][ni] = (floatx4)(0.f);

#pragma unroll
    for (int kp = 0; kp < KP; ++kp) {
        bf16x8 bfr[NI];
#pragma unroll
        for (int ni = 0; ni < NI; ++ni)
            bfr[ni] = *(const bf16x8*)&Bsm[((size_t)(kp * BN + ni * 16 + lr) * 4 + sw) * 8];
#pragma unroll
        for (int mi = 0; mi < 2; ++mi)
#pragma unroll
            for (int ni = 0; ni < NI; ++ni)
                acc[mi][ni] = __builtin_amdgcn_mfma_f32_16x16x32_bf16(
                    af[kp][mi], bfr[ni], acc[mi][ni], 0, 0, 0);
    }

    float bias_v[NI];
#pragma unroll
    for (int ni = 0; ni < NI; ++ni)
        bias_v[ni] = bias ? bias[col0 + ni * 16 + lr] : 0.f;
    float s_acc[NI], ss_acc[NI];
#pragma unroll
    for (int ni = 0; ni < NI; ++ni) { s_acc[ni] = 0.f; ss_acc[ni] = 0.f; }

    short* Cw = Csm + wv * 16 * BNP;
#pragma unroll
    for (int mi = 0; mi < 2; ++mi) {
        __builtin_amdgcn_wave_barrier();
#pragma unroll
        for (int r = 0; r < 4; ++r) {
            int gr = rbase + mi * 16 + lq * 4 + r;
            const float* subrow = nullptr;
            if (sub) {
                int bidx = batch[min(gr, M - 1)];
                subrow = &sub[(size_t)bidx * subld + col0];
            }
#pragma unroll
            for (int ni = 0; ni < NI; ++ni) {
                float v = acc[mi][ni][r] + bias_v[ni];
                if (sub) v -= subrow[ni * 16 + lr];
                if (do_relu) v = fmaxf(v, 0.f);
                if (bnpart && gr < M) {
                    float rv = fmaxf(v, 0.f);
                    s_acc[ni] += rv;
                    ss_acc[ni] = fmaf(rv, rv, ss_acc[ni]);
                }
                Cw[(lq * 4 + r) * BNP + ni * 16 + lr] = f2bf(v);
            }
        }
        __builtin_amdgcn_wave_barrier();
#pragma unroll
        for (int it = 0; it < BN / 32; ++it) {
            int t  = it * 64 + lane;
            int rl = t / (BN / 8);
            int chk = t % (BN / 8);
            uint4 d = *(const uint4*)&Cw[rl * BNP + chk * 8];
            int gr = rbase + mi * 16 + rl;
            *(uint4*)&Cb[(size_t)gr * ldc + col0 + chk * 8] = d;
        }
        __builtin_amdgcn_wave_barrier();
    }

    if (bnpart) {   // only used with BN=128, gridDim.y==1
#pragma unroll
        for (int ni = 0; ni < NI; ++ni) {
            float sv = s_acc[ni], ssv = ss_acc[ni];
            sv += __shfl_xor(sv, 16); sv += __shfl_xor(sv, 32);
            ssv += __shfl_xor(ssv, 16); ssv += __shfl_xor(ssv, 32);
            if (lq == 0) {
                bnred[wv * 256 + ni * 16 + lr] = sv;
                bnred[wv * 256 + 128 + ni * 16 + lr] = ssv;
            }
        }
        __syncthreads();
        if (tid < 256) {
            float t = bnred[tid] + bnred[256 + tid] + bnred[512 + tid] + bnred[768 + tid];
            bnpart[(size_t)blockIdx.x * 256 + tid] = t;
        }
    }
}

// ======= fused filtration: s0 = relu(relu(x@W_f1+b_f1)@W_eff+b_eff) ==========
// hidden (128x256 per block) lives only in LDS. Two 128-col halves.
__global__ __launch_bounds__(256, 1)
void filt_s0(const short* __restrict__ A,      // x_bf [Npad][128]
             const short* __restrict__ B1t,    // Wf1t [256][128]
             const float* __restrict__ b1,     // b_f1 [256]
             const short* __restrict__ B2t,    // Wefft [64][256]
             const float* __restrict__ b2,     // beff [64]
             short* __restrict__ Cb)           // s0_bf [Npad][64]
{
    __shared__ short B1s[128 * 128];  // 32 KB: half of W_f1^T (panel layout)
    __shared__ short B2s[64 * 256];   // 32 KB: W_eff^T full
    __shared__ short Hs[4 * 128 * 32];// 32 KB: hidden half (panel layout)

    const int tid  = threadIdx.x;
    const int lane = tid & 63;
    const int wv   = tid >> 6;
    const int lq   = lane >> 4;
    const int lr   = lane & 15;
    const int row0 = blockIdx.x * 128;
    const int rbase = row0 + wv * 32;
    const int sw   = lq ^ ((lr >> 1) & 3);

    // stage B2 (8 panels x 64 rows x 4 chunks)
#pragma unroll
    for (int rr = 0; rr < 8; ++rr) {
        int cidb = rr * 256 + wv * 64;
        int cid  = cidb + lane;
        int panel = cid >> 8;
        int rowc  = cid & 255;
        int row = rowc >> 2, c = rowc & 3;
        int cg  = c ^ ((row >> 1) & 3);
        async16(B2t + (size_t)row * 256 + panel * 32 + cg * 8, &B2s[(size_t)cidb * 8]);
    }
    // stage B1 half h (4 panels x 128 rows x 4 chunks)
    auto stageB1 = [&](int h) {
#pragma unroll
        for (int rr = 0; rr < 8; ++rr) {
            int cidb = rr * 256 + wv * 64;
            int cid  = cidb + lane;
            int panel = cid >> 9;
            int rowc  = cid & 511;
            int row = rowc >> 2, c = rowc & 3;
            int cg  = c ^ ((row >> 1) & 3);
            async16(B1t + (size_t)(h * 128 + row) * 128 + panel * 32 + cg * 8,
                    &B1s[(size_t)cidb * 8]);
        }
    };
    stageB1(0);

    bf16x8 af[4][2];
#pragma unroll
    for (int kp = 0; kp < 4; ++kp)
#pragma unroll
        for (int mi = 0; mi < 2; ++mi)
            af[kp][mi] = *(const bf16x8*)&A[(size_t)(rbase + mi * 16 + lr) * 128
                                            + kp * 32 + lq * 8];

    __syncthreads();

    floatx4 acc2[2][4];
#pragma unroll
    for (int mi = 0; mi < 2; ++mi)
#pragma unroll
        for (int ni = 0; ni < 4; ++ni) acc2[mi][ni] = (floatx4)(0.f);

#pragma unroll
    for (int h = 0; h < 2; ++h) {
        // MFMA1: hidden half = x @ W_f1[:, h*128 .. h*128+127]
        floatx4 acc1[2][8];
#pragma unroll
        for (int mi = 0; mi < 2; ++mi)
#pragma unroll
            for (int ni = 0; ni < 8; ++ni) acc1[mi][ni] = (floatx4)(0.f);
#pragma unroll
        for (int kp = 0; kp < 4; ++kp) {
            bf16x8 bfr[8];
#pragma unroll
            for (int ni = 0; ni < 8; ++ni)
                bfr[ni] = *(const bf16x8*)&B1s[((size_t)(kp * 128 + ni * 16 + lr) * 4 + sw) * 8];
#pragma unroll
            for (int mi = 0; mi < 2; ++mi)
#pragma unroll
                for (int ni = 0; ni < 8; ++ni)
                    acc1[mi][ni] = __builtin_amdgcn_mfma_f32_16x16x32_bf16(
                        af[kp][mi], bfr[ni], acc1[mi][ni], 0, 0, 0);
        }
        // relu + bias -> Hs (panel layout for MFMA2 A-frags)
#pragma unroll
        for (int mi = 0; mi < 2; ++mi)
#pragma unroll
            for (int r = 0; r < 4; ++r) {
                int m = wv * 32 + mi * 16 + lq * 4 + r;   // local row 0..127
                int mswz = (m >> 1) & 3;
#pragma unroll
                for (int ni = 0; ni < 8; ++ni) {
                    int n1 = ni * 16 + lr;
                    float v = fmaxf(acc1[mi][ni][r] + b1[h * 128 + n1], 0.f);
                    int pnl = n1 >> 5, c = (n1 >> 3) & 3;
                    Hs[((size_t)(pnl * 128 + m) * 4 + (c ^ mswz)) * 8 + (n1 & 7)] = f2bf(v);
                }
            }
        __syncthreads();               // Hs ready, B1s reads done
        if (h == 0) stageB1(1);        // overlap with MFMA2 below
        // MFMA2: acc2 += hidden_half @ W_eff[h*128 .. , :]
#pragma unroll
        for (int pp = 0; pp < 4; ++pp) {
            bf16x8 a2[2];
#pragma unroll
            for (int mi = 0; mi < 2; ++mi) {
                int row = wv * 32 + mi * 16 + lr;
                a2[mi] = *(const bf16x8*)&Hs[((size_t)(pp * 128 + row) * 4
                                              + (lq ^ ((row >> 1) & 3))) * 8];
            }
            bf16x8 b2f[4];
#pragma unroll
            for (int ni = 0; ni < 4; ++ni)
                b2f[ni] = *(const bf16x8*)&B2s[((size_t)((h * 4 + pp) * 64 + ni * 16 + lr) * 4
                                                + sw) * 8];
#pragma unroll
            for (int mi = 0; mi < 2; ++mi)
#pragma unroll
                for (int ni = 0; ni < 4; ++ni)
                    acc2[mi][ni] = __builtin_amdgcn_mfma_f32_16x16x32_bf16(
                        a2[mi], b2f[ni], acc2[mi][ni], 0, 0, 0);
        }
        if (h == 0) __syncthreads();   // B1 half1 arrived; Hs reads done
    }

    // epilogue: relu(acc2 + b2) -> Cb, wave-private LDS slice in B1s
    float bias2v[4];
#pragma unroll
    for (int ni = 0; ni < 4; ++ni) bias2v[ni] = b2[ni * 16 + lr];
    short* Cw = B1s + wv * 16 * 72;
#pragma unroll
    for (int mi = 0; mi < 2; ++mi) {
        __builtin_amdgcn_wave_barrier();
#pragma unroll
        for (int r = 0; r < 4; ++r)
#pragma unroll
            for (int ni = 0; ni < 4; ++ni) {
                float v = fmaxf(acc2[mi][ni][r] + bias2v[ni], 0.f);
                Cw[(lq * 4 + r) * 72 + ni * 16 + lr] = f2bf(v);
            }
        __builtin_amdgcn_wave_barrier();
#pragma unroll
        for (int it = 0; it < 2; ++it) {
            int t = it * 64 + lane;
            int rl = t >> 3, chk = t & 7;
            uint4 d = *(const uint4*)&Cw[rl * 72 + chk * 8];
            int gr = rbase + mi * 16 + rl;
            *(uint4*)&Cb[(size_t)gr * 64 + chk * 8] = d;
        }
        __builtin_amdgcn_wave_barrier();
    }
}

// ---------------- pack x -> bf16 (padded) + per-node a=x.u, b=x.v ------------
__global__ __launch_bounds__(256)
void pack_x(const float* __restrict__ x, const float* __restrict__ u,
            const float* __restrict__ v, short* __restrict__ x_bf,
            float* __restrict__ a, float* __restrict__ b, int N, int Npad)
{
    int t = blockIdx.x * 256 + threadIdx.x;
    int n = t >> 4, j = t & 15;
    if (n >= Npad) return;
    if (n >= N) {
        *(uint4*)&x_bf[(size_t)n * 128 + j * 8] = make_uint4(0, 0, 0, 0);
        return;
    }
    const float* xr = x + (size_t)n * 128 + j * 8;
    float4 x0 = *(const float4*)xr;
    float4 x1 = *(const float4*)(xr + 4);
    union { short s[8]; uint4 q; } pk;
    pk.s[0] = f2bf(x0.x); pk.s[1] = f2bf(x0.y); pk.s[2] = f2bf(x0.z); pk.s[3] = f2bf(x0.w);
    pk.s[4] = f2bf(x1.x); pk.s[5] = f2bf(x1.y); pk.s[6] = f2bf(x1.z); pk.s[7] = f2bf(x1.w);
    *(uint4*)&x_bf[(size_t)n * 128 + j * 8] = pk.q;
    const float* up = u + j * 8;
    const float* vp = v + j * 8;
    float sa = x0.x*up[0] + x0.y*up[1] + x0.z*up[2] + x0.w*up[3]
             + x1.x*up[4] + x1.y*up[5] + x1.z*up[6] + x1.w*up[7];
    float sb = x0.x*vp[0] + x0.y*vp[1] + x0.z*vp[2] + x0.w*vp[3]
             + x1.x*vp[4] + x1.y*vp[5] + x1.z*vp[6] + x1.w*vp[7];
    sa += __shfl_xor(sa, 1); sa += __shfl_xor(sa, 2);
    sa += __shfl_xor(sa, 4); sa += __shfl_xor(sa, 8);
    sb += __shfl_xor(sb, 1); sb += __shfl_xor(sb, 2);
    sb += __shfl_xor(sb, 4); sb += __shfl_xor(sb, 8);
    if (j == 0) { a[n] = sa; b[n] = sb; }
}

// ---- attention fold: T[h] = A_h @ W_h^T -------------------------------------
__global__ __launch_bounds__(128)
void att_fold1(const float* __restrict__ A_att, const float* __restrict__ W_att,
               float* __restrict__ T)
{
    int h = blockIdx.y, i = blockIdx.x, j = threadIdx.x;
    const float* A = A_att + (size_t)h * 16384;
    const float* W = W_att + (size_t)h * 16384;
    float s = 0.f;
    for (int k = 0; k < 128; ++k) s = fmaf(A[i * 128 + k], W[j * 128 + k], s);
    T[(size_t)h * 16384 + i * 128 + j] = s;
}

// ---- Mt[n][k] = (sum_h W_h@T_h)[k][n] bf16 ----------------------------------
__global__ __launch_bounds__(128)
void att_fold2(const float* __restrict__ W_att, const float* __restrict__ T,
               short* __restrict__ Mt)
{
    int i = blockIdx.x, j = threadIdx.x;
    float s = 0.f;
    for (int h = 0; h < HEADS; ++h) {
        const float* W = W_att + (size_t)h * 16384 + i * 128;
        const float* Th = T + (size_t)h * 16384;
        for (int k = 0; k < 128; ++k) s = fmaf(W[k], Th[k * 128 + j], s);
    }
    Mt[(size_t)j * 128 + i] = f2bf(s);
}

// ---- u = sum W_h(A_h b_h), v = sum (b_h A_h)W_h^T, c0 = sum b_h.(A_h b_h) ---
__global__ __launch_bounds__(128)
void att_fold3(const float* __restrict__ W_att, const float* __restrict__ b_att,
               const float* __restrict__ A_att,
               float* __restrict__ u, float* __restrict__ v, float* __restrict__ c0)
{
    __shared__ float tb[HEADS][128], tv[HEADS][128];
    int t = threadIdx.x;
    for (int h = 0; h < HEADS; ++h) {
        const float* A = A_att + (size_t)h * 16384;
        const float* b = b_att + h * 128;
        float sb = 0.f, sv = 0.f;
        for (int j = 0; j < 128; ++j) {
            sb = fmaf(A[t * 128 + j], b[j], sb);
            sv = fmaf(b[j], A[j * 128 + t], sv);
        }
        tb[h][t] = sb; tv[h][t] = sv;
    }
    __syncthreads();
    float su = 0.f, sv2 = 0.f;
    for (int h = 0; h < HEADS; ++h) {
        const float* W = W_att + (size_t)h * 16384 + t * 128;
        for (int k = 0; k < 128; ++k) {
            su = fmaf(W[k], tb[h][k], su);
            sv2 = fmaf(W[k], tv[h][k], sv2);
        }
    }
    u[t] = su; v[t] = sv2;
    if (t == 0) {
        float c = 0.f;
        for (int h = 0; h < HEADS; ++h)
            for (int k = 0; k < 128; ++k) c += b_att[h * 128 + k] * tb[h][k];
        *c0 = c;
    }
}

// ---- edge attention: sigmoid(0.25*(q[r].x[c] + a[r] + b[c] + c0)) -----------
__global__ __launch_bounds__(256)
void edge_att(const short* __restrict__ q, const short* __restrict__ xb,
              const int* __restrict__ row, const int* __restrict__ col,
              const float* __restrict__ a, const float* __restrict__ b,
              const float* __restrict__ c0, float* __restrict__ att, int E)
{
    int t = blockIdx.x * 256 + threadIdx.x;
    int e = t >> 4, j = t & 15;
    if (e >= E) return;
    int r = row[e], c = col[e];
    uint4 qa = *(const uint4*)&q[(size_t)r * 128 + j * 8];
    uint4 xa = *(const uint4*)&xb[(size_t)c * 128 + j * 8];
    float p = dot2(qa.x, xa.x) + dot2(qa.y, xa.y) + dot2(qa.z, xa.z) + dot2(qa.w, xa.w);
    p += __shfl_xor(p, 1); p += __shfl_xor(p, 2);
    p += __shfl_xor(p, 4); p += __shfl_xor(p, 8);
    if (j == 0) {
        float s = 0.25f * (p + a[r] + b[c] + *c0);
        att[e] = 1.f / (1.f + expf(-s));
    }
}

// --------- Wf1t[c][r] = W_f1[r][c] bf16 (256x128) ----------------------------
__global__ __launch_bounds__(256)
void wf1_transpose(const float* __restrict__ W, short* __restrict__ Wt)
{
    int r = blockIdx.x;
    int c = threadIdx.x;
    Wt[(size_t)c * 128 + r] = f2bf(W[(size_t)r * 256 + c]);
}

// --------- G1 (64x64) -> G1t bf16; G2 (64x128) -> G2t[128][64] bf16 ----------
__global__ __launch_bounds__(64)
void transpose_g(const float* __restrict__ G1, const float* __restrict__ G2,
                 short* __restrict__ G1t, short* __restrict__ G2t)
{
    int b = blockIdx.x;
    int j = threadIdx.x;
    if (b < 64) {
        G1t[(size_t)j * 64 + b] = f2bf(G1[(size_t)b * 64 + j]);
    } else {
        int n = b - 64;
        G2t[(size_t)n * 64 + j] = f2bf(G2[(size_t)j * 128 + n]);
    }
}

// ---- Wefft[o][k] = (W_f2 @ (W_l0[2j]+W_l0[2j+1]))[k][o] bf16; beff fp32 -----
__global__ __launch_bounds__(64)
void build_weff(const float* __restrict__ W_f2, const float* __restrict__ b_f2,
                const float* __restrict__ W_l0, const float* __restrict__ b_l0,
                short* __restrict__ Wefft, float* __restrict__ beff)
{
    int o = threadIdx.x;
    int k = blockIdx.x;
    if (k < 256) {
        float a = 0.f;
        for (int j = 0; j < 8; ++j) {
            float w = W_l0[(2 * j) * 64 + o] + W_l0[(2 * j + 1) * 64 + o];
            a = fmaf(W_f2[k * 8 + j], w, a);
        }
        Wefft[(size_t)o * 256 + k] = f2bf(a);
    } else {
        float a = b_l0[o];
        for (int j = 0; j < 8; ++j) {
            float w = W_l0[(2 * j) * 64 + o] + W_l0[(2 * j + 1) * 64 + o];
            a = fmaf(b_f2[j], w, a);
        }
        beff[o] = a;
    }
}

// -------- segment sums over sorted batch, 64 bf16 features -------------------
__global__ __launch_bounds__(256)
void segmean_bf(const short* __restrict__ v, const int* __restrict__ batch,
                float* __restrict__ sums, float* __restrict__ cnt,
                int N, int do_cnt)
{
    const int lane = threadIdx.x & 63;
    const int wv = threadIdx.x >> 6;
    const int lq = lane >> 4;
    const int lr = lane & 15;
    int start = (blockIdx.x * 4 + wv) * 64;
    if (start >= N) return;
    int end = min(start + 64, N);
    int i = start + lq;
    float4 a = make_float4(0.f, 0.f, 0.f, 0.f);
    float run = 0.f;
    int cur = (i < end) ? batch[i] : -1;
    for (; i < end; i += 4) {
        int g = batch[i];
        if (g != cur) {
            float* s = &sums[(size_t)cur * 64 + lr * 4];
            atomicAdd(&s[0], a.x); atomicAdd(&s[1], a.y);
            atomicAdd(&s[2], a.z); atomicAdd(&s[3], a.w);
            if (do_cnt && lr == 0) atomicAdd(&cnt[cur], run);
            cur = g; a = make_float4(0.f, 0.f, 0.f, 0.f); run = 0.f;
        }
        uint2 d = *(const uint2*)&v[(size_t)i * 64 + lr * 4];
        a.x += bflo(d.x); a.y += bfhi(d.x);
        a.z += bflo(d.y); a.w += bfhi(d.y);
        run += 1.f;
    }
    if (cur >= 0) {
        float* s = &sums[(size_t)cur * 64 + lr * 4];
        atomicAdd(&s[0], a.x); atomicAdd(&s[1], a.y);
        atomicAdd(&s[2], a.z); atomicAdd(&s[3], a.w);
        if (do_cnt && lr == 0) atomicAdd(&cnt[cur], run);
    }
}

__global__ void xm_compute(const float* __restrict__ sums, const float* __restrict__ cnt,
                           const float* __restrict__ L, float* __restrict__ xm, int Fout)
{
    int g = blockIdx.x;
    int j = threadIdx.x;
    float inv = 1.f / fmaxf(cnt[g], 1.f);
    float a = 0.f;
    for (int k = 0; k < 64; ++k)
        a = fmaf(sums[g * 64 + k] * inv, L[k * Fout + j], a);
    xm[g * Fout + j] = a;
}

// ---- reduce per-block BN partials + compute scale/shift ---------------------
__global__ __launch_bounds__(256)
void bn_final2(const float* __restrict__ part, int nblk,
               const float* __restrict__ gamma, const float* __restrict__ beta,
               float* __restrict__ scale, float* __restrict__ shift, float invN)
{
    int j = threadIdx.x;
    float a0 = 0.f, a1 = 0.f, a2 = 0.f, a3 = 0.f;
    float a4 = 0.f, a5 = 0.f, a6 = 0.f, a7 = 0.f;
    int b = 0;
    for (; b + 8 <= nblk; b += 8) {
        a0 += part[(size_t)(b + 0) * 256 + j];
        a1 += part[(size_t)(b + 1) * 256 + j];
        a2 += part[(size_t)(b + 2) * 256 + j];
        a3 += part[(size_t)(b + 3) * 256 + j];
        a4 += part[(size_t)(b + 4) * 256 + j];
        a5 += part[(size_t)(b + 5) * 256 + j];
        a6 += part[(size_t)(b + 6) * 256 + j];
        a7 += part[(size_t)(b + 7) * 256 + j];
    }
    for (; b < nblk; ++b) a0 += part[(size_t)b * 256 + j];
    float t = ((a0 + a1) + (a2 + a3)) + ((a4 + a5) + (a6 + a7));
    __shared__ float tot[256];
    tot[j] = t;
    __syncthreads();
    if (j < 128) {
        float mu = tot[j] * invN;
        float var = tot[128 + j] * invN - mu * mu;
        float sc = gamma[j] * rsqrtf(var + 1e-5f);
        scale[j] = sc;
        shift[j] = beta[j] - mu * sc;
    }
}

// ---------------- out = x + relu(x0_bf)*scale + shift ------------------------
__global__ __launch_bounds__(256)
void finalize(const float* __restrict__ x, const short* __restrict__ x0b,
              const float* __restrict__ scale, const float* __restrict__ shift,
              float* __restrict__ out, int total4)
{
    int i = blockIdx.x * blockDim.x + threadIdx.x;
    if (i >= total4) return;
    int f0 = (i * 4) & 127;
    uint2 h2 = ((const uint2*)x0b)[i];
    float4 xv = ((const float4*)x)[i];
    float4 sc = *(const float4*)&scale[f0];
    float4 sh = *(const float4*)&shift[f0];
    float4 o;
    o.x = xv.x + fmaxf(bflo(h2.x), 0.f) * sc.x + sh.x;
    o.y = xv.y + fmaxf(bfhi(h2.x), 0.f) * sc.y + sh.y;
    o.z = xv.z + fmaxf(bflo(h2.y), 0.f) * sc.z + sh.z;
    o.w = xv.w + fmaxf(bfhi(h2.y), 0.f) * sc.w + sh.w;
    ((float4*)out)[i] = o;
}

extern "C" void kernel_launch(void* const* d_in, const int* in_sizes, int n_in,
                              void* d_out, int out_size, void* d_ws, size_t ws_size,
                              hipStream_t stream)
{
    const float* x      = (const float*)d_in[0];
    const int*   ei     = (const int*)d_in[1];
    const int*   batch  = (const int*)d_in[2];
    const float* W_f1   = (const float*)d_in[3];
    const float* b_f1   = (const float*)d_in[4];
    const float* W_f2   = (const float*)d_in[5];
    const float* b_f2   = (const float*)d_in[6];
    const float* W_l0   = (const float*)d_in[7];
    const float* b_l0   = (const float*)d_in[8];
    const float* G1     = (const float*)d_in[9];
    const float* b_g1   = (const float*)d_in[10];
    const float* L1     = (const float*)d_in[11];
    const float* G2     = (const float*)d_in[12];
    const float* b_g2   = (const float*)d_in[13];
    const float* L2     = (const float*)d_in[14];
    const float* gam    = (const float*)d_in[15];
    const float* bet    = (const float*)d_in[16];
    const float* W_att  = (const float*)d_in[17];
    const float* b_att  = (const float*)d_in[18];
    const float* A_att  = (const float*)d_in[19];

    const int N = in_sizes[2];
    const int E = in_sizes[1] / 2;
    const int Npad = (N + 127) & ~127;
    const int gmm = Npad / 128;

    char* p = (char*)d_ws;
    auto alloc = [&](size_t bytes) {
        char* r = p;
        p += (bytes + 255) & ~(size_t)255;
        return r;
    };

    short* x_bf   = (short*)alloc((size_t)Npad * 128 * 2);
    short* q_bf   = (short*)alloc((size_t)Npad * 128 * 2);
    short* s0_bf  = (short*)alloc((size_t)Npad * 64 * 2);
    short* s1_bf  = (short*)alloc((size_t)Npad * 64 * 2);
    short* x0_bf  = (short*)alloc((size_t)Npad * 128 * 2);
    float* a_arr  = (float*)alloc((size_t)N * 4);
    float* b_arr  = (float*)alloc((size_t)N * 4);
    float* bnpart = (float*)alloc((size_t)gmm * 256 * 4);
    float* Tbuf   = (float*)alloc((size_t)HEADS * 128 * 128 * 4);
    short* Mt     = (short*)alloc(128 * 128 * 2);
    float* u_v    = (float*)alloc(128 * 4);
    float* v_v    = (float*)alloc(128 * 4);
    float* c0_v   = (float*)alloc(4);
    short* Wf1t   = (short*)alloc(256 * 128 * 2);
    short* Wefft  = (short*)alloc(64 * 256 * 2);
    float* beff   = (float*)alloc(64 * 4);
    short* G1t    = (short*)alloc(64 * 64 * 2);
    short* G2t    = (short*)alloc(128 * 64 * 2);
    float* zblk   = (float*)alloc((64 * 64 * 2 + 64) * 4);
    float* xm1    = (float*)alloc(64 * 64 * 4);
    float* xm2    = (float*)alloc(64 * 128 * 4);
    float* bscale = (float*)alloc(128 * 4);
    float* bshift = (float*)alloc(128 * 4);

    if ((size_t)(p - (char*)d_ws) > ws_size) return;

    float* sums1 = zblk;
    float* sums2 = zblk + 64 * 64;
    float* cnt   = zblk + 64 * 64 * 2;

    float* out0    = (float*)d_out;
    float* att_out = out0 + (size_t)N * 128;

    hipMemsetAsync(zblk, 0, (64 * 64 * 2 + 64) * 4, stream);

    // prologue: fold attention, build weights
    att_fold1<<<dim3(128, HEADS), 128, 0, stream>>>(A_att, W_att, Tbuf);
    att_fold2<<<128, 128, 0, stream>>>(W_att, Tbuf, Mt);
    att_fold3<<<1, 128, 0, stream>>>(W_att, b_att, A_att, u_v, v_v, c0_v);
    pack_x<<<(Npad * 16 + 255) / 256, 256, 0, stream>>>(x, u_v, v_v, x_bf,
                                                        a_arr, b_arr, N, Npad);
    wf1_transpose<<<128, 256, 0, stream>>>(W_f1, Wf1t);
    build_weff<<<257, 64, 0, stream>>>(W_f2, b_f2, W_l0, b_l0, Wefft, beff);
    transpose_g<<<192, 64, 0, stream>>>(G1, G2, G1t, G2t);

    // q = x @ M
    gemm_rk<128, 128><<<dim3(gmm, 1), 256, 0, stream>>>(
        x_bf, 128, Mt, nullptr, nullptr, 0, nullptr, q_bf, 128,
        nullptr, N, 0);
    edge_att<<<(E * 16 + 255) / 256, 256, 0, stream>>>(
        q_bf, x_bf, ei, ei + E, a_arr, b_arr, c0_v, att_out, E);

    // s0 = relu(relu(x@W_f1+b_f1)@W_eff+b_eff), hidden in LDS only
    filt_s0<<<gmm, 256, 0, stream>>>(x_bf, Wf1t, b_f1, Wefft, beff, s0_bf);

    segmean_bf<<<(N + 255) / 256, 256, 0, stream>>>(s0_bf, batch, sums1, cnt, N, 1);
    xm_compute<<<64, 64, 0, stream>>>(sums1, cnt, L1, xm1, 64);
    gemm_rk<64, 64><<<dim3(gmm, 1), 256, 0, stream>>>(
        s0_bf, 64, G1t, b_g1, xm1, 64, batch, s1_bf, 64,
        nullptr, N, 1);
    segmean_bf<<<(N + 255) / 256, 256, 0, stream>>>(s1_bf, batch, sums2, cnt, N, 0);
    xm_compute<<<64, 128, 0, stream>>>(sums2, cnt, L2, xm2, 128);
    gemm_rk<64, 128><<<dim3(gmm, 1), 256, 0, stream>>>(
        s1_bf, 64, G2t, b_g2, xm2, 128, batch, x0_bf, 128,
        bnpart, N, 0);

    bn_final2<<<1, 256, 0, stream>>>(bnpart, gmm, gam, bet, bscale, bshift, 1.f / (float)N);
    finalize<<<((N * 128 / 4) + 255) / 256, 256, 0, stream>>>(x, x0_bf, bscale, bshift,
                                                              out0, N * 128 / 4);
}

// Round 7
// 355.489 us; speedup vs baseline: 1.3907x; 1.2713x over previous
//
#include <hip/hip_runtime.h>
#include <cstdint>

#define HEADS 4

typedef __attribute__((ext_vector_type(8))) short bf16x8;
typedef __attribute__((ext_vector_type(4))) float floatx4;

__device__ __forceinline__ short f2bf(float f) {
    union { float f; unsigned u; } v; v.f = f;
    unsigned r = v.u + 0x7FFFu + ((v.u >> 16) & 1u);
    return (short)(r >> 16);
}
__device__ __forceinline__ float bflo(unsigned u) {
    union { unsigned u; float f; } v; v.u = u << 16; return v.f;
}
__device__ __forceinline__ float bfhi(unsigned u) {
    union { unsigned u; float f; } v; v.u = u & 0xffff0000u; return v.f;
}
__device__ __forceinline__ float dot2(unsigned a, unsigned b) {
    return bflo(a) * bflo(b) + bfhi(a) * bfhi(b);
}
__device__ __forceinline__ void async16(const void* g, void* l) {
    __builtin_amdgcn_global_load_lds((const __attribute__((address_space(1))) void*)g,
                                     (__attribute__((address_space(3))) void*)l,
                                     16, 0, 0);
}

// ============== skinny-K bf16 MFMA GEMM: B resident in LDS, A direct =========
template<int K, int BN>
__global__ __launch_bounds__(256)
void gemm_rk(const short* __restrict__ A, int lda,
             const short* __restrict__ Bt,
             const float* __restrict__ bias,
             const float* __restrict__ sub, int subld,
             const int* __restrict__ batch,
             short* __restrict__ Cb, int ldc,
             float* __restrict__ bnpart,
             int M, int do_relu)
{
    constexpr int NI  = BN / 16;
    constexpr int KP  = K / 32;
    constexpr int BNP = BN + 8;
    __shared__ short smem[BN * K + 64 * BNP];
    __shared__ float bnred[4 * 256];
    short* Bsm = smem;
    short* Csm = smem + BN * K;

    const int tid  = threadIdx.x;
    const int lane = tid & 63;
    const int wv   = tid >> 6;
    const int lq   = lane >> 4;
    const int lr   = lane & 15;
    const int row0 = blockIdx.x * 128;
    const int col0 = blockIdx.y * BN;
    const int sw   = lq ^ ((lr >> 1) & 3);

    const short* gB = Bt + (size_t)col0 * K;
    constexpr int ROUNDS = (KP * BN * 4) / 256;
#pragma unroll
    for (int rr = 0; rr < ROUNDS; ++rr) {
        int cidb = rr * 256 + wv * 64;
        int cid  = cidb + lane;
        int panel = cid / (BN * 4);
        int rowc  = cid % (BN * 4);
        int row = rowc >> 2, c = rowc & 3;
        int cg  = c ^ ((row >> 1) & 3);
        async16(gB + (size_t)row * K + panel * 32 + cg * 8, &Bsm[(size_t)cidb * 8]);
    }

    const int rbase = row0 + wv * 32;
    bf16x8 af[KP][2];
#pragma unroll
    for (int kp = 0; kp < KP; ++kp)
#pragma unroll
        for (int mi = 0; mi < 2; ++mi)
            af[kp][mi] = *(const bf16x8*)&A[(size_t)(rbase + mi * 16 + lr) * lda
                                            + kp * 32 + lq * 8];

    __syncthreads();

    floatx4 acc[2][NI];
#pragma unroll
    for (int mi = 0; mi < 2; ++mi)
#pragma unroll
        for (int ni = 0; ni < NI; ++ni) acc[mi][ni] = (floatx4)(0.f);

#pragma unroll
    for (int kp = 0; kp < KP; ++kp) {
        bf16x8 bfr[NI];
#pragma unroll
        for (int ni = 0; ni < NI; ++ni)
            bfr[ni] = *(const bf16x8*)&Bsm[((size_t)(kp * BN + ni * 16 + lr) * 4 + sw) * 8];
#pragma unroll
        for (int mi = 0; mi < 2; ++mi)
#pragma unroll
            for (int ni = 0; ni < NI; ++ni)
                acc[mi][ni] = __builtin_amdgcn_mfma_f32_16x16x32_bf16(
                    af[kp][mi], bfr[ni], acc[mi][ni], 0, 0, 0);
    }

    float bias_v[NI];
#pragma unroll
    for (int ni = 0; ni < NI; ++ni)
        bias_v[ni] = bias ? bias[col0 + ni * 16 + lr] : 0.f;
    float s_acc[NI], ss_acc[NI];
#pragma unroll
    for (int ni = 0; ni < NI; ++ni) { s_acc[ni] = 0.f; ss_acc[ni] = 0.f; }

    short* Cw = Csm + wv * 16 * BNP;
#pragma unroll
    for (int mi = 0; mi < 2; ++mi) {
        __builtin_amdgcn_wave_barrier();
#pragma unroll
        for (int r = 0; r < 4; ++r) {
            int gr = rbase + mi * 16 + lq * 4 + r;
            const float* subrow = nullptr;
            if (sub) {
                int bidx = batch[min(gr, M - 1)];
                subrow = &sub[(size_t)bidx * subld + col0];
            }
#pragma unroll
            for (int ni = 0; ni < NI; ++ni) {
                float v = acc[mi][ni][r] + bias_v[ni];
                if (sub) v -= subrow[ni * 16 + lr];
                if (do_relu) v = fmaxf(v, 0.f);
                if (bnpart && gr < M) {
                    float rv = fmaxf(v, 0.f);
                    s_acc[ni] += rv;
                    ss_acc[ni] = fmaf(rv, rv, ss_acc[ni]);
                }
                Cw[(lq * 4 + r) * BNP + ni * 16 + lr] = f2bf(v);
            }
        }
        __builtin_amdgcn_wave_barrier();
#pragma unroll
        for (int it = 0; it < BN / 32; ++it) {
            int t  = it * 64 + lane;
            int rl = t / (BN / 8);
            int chk = t % (BN / 8);
            uint4 d = *(const uint4*)&Cw[rl * BNP + chk * 8];
            int gr = rbase + mi * 16 + rl;
            *(uint4*)&Cb[(size_t)gr * ldc + col0 + chk * 8] = d;
        }
        __builtin_amdgcn_wave_barrier();
    }

    if (bnpart) {   // only used with BN=128, gridDim.y==1
#pragma unroll
        for (int ni = 0; ni < NI; ++ni) {
            float sv = s_acc[ni], ssv = ss_acc[ni];
            sv += __shfl_xor(sv, 16); sv += __shfl_xor(sv, 32);
            ssv += __shfl_xor(ssv, 16); ssv += __shfl_xor(ssv, 32);
            if (lq == 0) {
                bnred[wv * 256 + ni * 16 + lr] = sv;
                bnred[wv * 256 + 128 + ni * 16 + lr] = ssv;
            }
        }
        __syncthreads();
        if (tid < 256) {
            float t = bnred[tid] + bnred[256 + tid] + bnred[512 + tid] + bnred[768 + tid];
            bnpart[(size_t)blockIdx.x * 256 + tid] = t;
        }
    }
}

// ======= fused filtration: s0 = relu(relu(x@W_f1+b_f1)@W_eff+b_eff) ==========
__global__ __launch_bounds__(256, 1)
void filt_s0(const short* __restrict__ A,      // x_bf [Npad][128]
             const short* __restrict__ B1t,    // Wf1t [256][128]
             const float* __restrict__ b1,     // b_f1 [256]
             const short* __restrict__ B2t,    // Wefft [64][256]
             const float* __restrict__ b2,     // beff [64]
             short* __restrict__ Cb)           // s0_bf [Npad][64]
{
    __shared__ short B1s[128 * 128];
    __shared__ short B2s[64 * 256];
    __shared__ short Hs[4 * 128 * 32];

    const int tid  = threadIdx.x;
    const int lane = tid & 63;
    const int wv   = tid >> 6;
    const int lq   = lane >> 4;
    const int lr   = lane & 15;
    const int row0 = blockIdx.x * 128;
    const int rbase = row0 + wv * 32;
    const int sw   = lq ^ ((lr >> 1) & 3);

#pragma unroll
    for (int rr = 0; rr < 8; ++rr) {
        int cidb = rr * 256 + wv * 64;
        int cid  = cidb + lane;
        int panel = cid >> 8;
        int rowc  = cid & 255;
        int row = rowc >> 2, c = rowc & 3;
        int cg  = c ^ ((row >> 1) & 3);
        async16(B2t + (size_t)row * 256 + panel * 32 + cg * 8, &B2s[(size_t)cidb * 8]);
    }
    auto stageB1 = [&](int h) {
#pragma unroll
        for (int rr = 0; rr < 8; ++rr) {
            int cidb = rr * 256 + wv * 64;
            int cid  = cidb + lane;
            int panel = cid >> 9;
            int rowc  = cid & 511;
            int row = rowc >> 2, c = rowc & 3;
            int cg  = c ^ ((row >> 1) & 3);
            async16(B1t + (size_t)(h * 128 + row) * 128 + panel * 32 + cg * 8,
                    &B1s[(size_t)cidb * 8]);
        }
    };
    stageB1(0);

    bf16x8 af[4][2];
#pragma unroll
    for (int kp = 0; kp < 4; ++kp)
#pragma unroll
        for (int mi = 0; mi < 2; ++mi)
            af[kp][mi] = *(const bf16x8*)&A[(size_t)(rbase + mi * 16 + lr) * 128
                                            + kp * 32 + lq * 8];

    __syncthreads();

    floatx4 acc2[2][4];
#pragma unroll
    for (int mi = 0; mi < 2; ++mi)
#pragma unroll
        for (int ni = 0; ni < 4; ++ni) acc2[mi][ni] = (floatx4)(0.f);

#pragma unroll
    for (int h = 0; h < 2; ++h) {
        floatx4 acc1[2][8];
#pragma unroll
        for (int mi = 0; mi < 2; ++mi)
#pragma unroll
            for (int ni = 0; ni < 8; ++ni) acc1[mi][ni] = (floatx4)(0.f);
#pragma unroll
        for (int kp = 0; kp < 4; ++kp) {
            bf16x8 bfr[8];
#pragma unroll
            for (int ni = 0; ni < 8; ++ni)
                bfr[ni] = *(const bf16x8*)&B1s[((size_t)(kp * 128 + ni * 16 + lr) * 4 + sw) * 8];
#pragma unroll
            for (int mi = 0; mi < 2; ++mi)
#pragma unroll
                for (int ni = 0; ni < 8; ++ni)
                    acc1[mi][ni] = __builtin_amdgcn_mfma_f32_16x16x32_bf16(
                        af[kp][mi], bfr[ni], acc1[mi][ni], 0, 0, 0);
        }
#pragma unroll
        for (int mi = 0; mi < 2; ++mi)
#pragma unroll
            for (int r = 0; r < 4; ++r) {
                int m = wv * 32 + mi * 16 + lq * 4 + r;
                int mswz = (m >> 1) & 3;
#pragma unroll
                for (int ni = 0; ni < 8; ++ni) {
                    int n1 = ni * 16 + lr;
                    float v = fmaxf(acc1[mi][ni][r] + b1[h * 128 + n1], 0.f);
                    int pnl = n1 >> 5, c = (n1 >> 3) & 3;
                    Hs[((size_t)(pnl * 128 + m) * 4 + (c ^ mswz)) * 8 + (n1 & 7)] = f2bf(v);
                }
            }
        __syncthreads();
        if (h == 0) stageB1(1);
#pragma unroll
        for (int pp = 0; pp < 4; ++pp) {
            bf16x8 a2[2];
#pragma unroll
            for (int mi = 0; mi < 2; ++mi) {
                int row = wv * 32 + mi * 16 + lr;
                a2[mi] = *(const bf16x8*)&Hs[((size_t)(pp * 128 + row) * 4
                                              + (lq ^ ((row >> 1) & 3))) * 8];
            }
            bf16x8 b2f[4];
#pragma unroll
            for (int ni = 0; ni < 4; ++ni)
                b2f[ni] = *(const bf16x8*)&B2s[((size_t)((h * 4 + pp) * 64 + ni * 16 + lr) * 4
                                                + sw) * 8];
#pragma unroll
            for (int mi = 0; mi < 2; ++mi)
#pragma unroll
                for (int ni = 0; ni < 4; ++ni)
                    acc2[mi][ni] = __builtin_amdgcn_mfma_f32_16x16x32_bf16(
                        a2[mi], b2f[ni], acc2[mi][ni], 0, 0, 0);
        }
        if (h == 0) __syncthreads();
    }

    float bias2v[4];
#pragma unroll
    for (int ni = 0; ni < 4; ++ni) bias2v[ni] = b2[ni * 16 + lr];
    short* Cw = B1s + wv * 16 * 72;
#pragma unroll
    for (int mi = 0; mi < 2; ++mi) {
        __builtin_amdgcn_wave_barrier();
#pragma unroll
        for (int r = 0; r < 4; ++r)
#pragma unroll
            for (int ni = 0; ni < 4; ++ni) {
                float v = fmaxf(acc2[mi][ni][r] + bias2v[ni], 0.f);
                Cw[(lq * 4 + r) * 72 + ni * 16 + lr] = f2bf(v);
            }
        __builtin_amdgcn_wave_barrier();
#pragma unroll
        for (int it = 0; it < 2; ++it) {
            int t = it * 64 + lane;
            int rl = t >> 3, chk = t & 7;
            uint4 d = *(const uint4*)&Cw[rl * 72 + chk * 8];
            int gr = rbase + mi * 16 + rl;
            *(uint4*)&Cb[(size_t)gr * 64 + chk * 8] = d;
        }
        __builtin_amdgcn_wave_barrier();
    }
}

// ---------------- pack x -> bf16 (padded) + per-node a=x.u, b=x.v ------------
__global__ __launch_bounds__(256)
void pack_x(const float* __restrict__ x, const float* __restrict__ u,
            const float* __restrict__ v, short* __restrict__ x_bf,
            float* __restrict__ a, float* __restrict__ b, int N, int Npad)
{
    int t = blockIdx.x * 256 + threadIdx.x;
    int n = t >> 4, j = t & 15;
    if (n >= Npad) return;
    if (n >= N) {
        *(uint4*)&x_bf[(size_t)n * 128 + j * 8] = make_uint4(0, 0, 0, 0);
        return;
    }
    const float* xr = x + (size_t)n * 128 + j * 8;
    float4 x0 = *(const float4*)xr;
    float4 x1 = *(const float4*)(xr + 4);
    union { short s[8]; uint4 q; } pk;
    pk.s[0] = f2bf(x0.x); pk.s[1] = f2bf(x0.y); pk.s[2] = f2bf(x0.z); pk.s[3] = f2bf(x0.w);
    pk.s[4] = f2bf(x1.x); pk.s[5] = f2bf(x1.y); pk.s[6] = f2bf(x1.z); pk.s[7] = f2bf(x1.w);
    *(uint4*)&x_bf[(size_t)n * 128 + j * 8] = pk.q;
    const float* up = u + j * 8;
    const float* vp = v + j * 8;
    float sa = x0.x*up[0] + x0.y*up[1] + x0.z*up[2] + x0.w*up[3]
             + x1.x*up[4] + x1.y*up[5] + x1.z*up[6] + x1.w*up[7];
    float sb = x0.x*vp[0] + x0.y*vp[1] + x0.z*vp[2] + x0.w*vp[3]
             + x1.x*vp[4] + x1.y*vp[5] + x1.z*vp[6] + x1.w*vp[7];
    sa += __shfl_xor(sa, 1); sa += __shfl_xor(sa, 2);
    sa += __shfl_xor(sa, 4); sa += __shfl_xor(sa, 8);
    sb += __shfl_xor(sb, 1); sb += __shfl_xor(sb, 2);
    sb += __shfl_xor(sb, 4); sb += __shfl_xor(sb, 8);
    if (j == 0) { a[n] = sa; b[n] = sb; }
}

// ---- attention fold: T[h] = A_h @ W_h^T -------------------------------------
__global__ __launch_bounds__(128)
void att_fold1(const float* __restrict__ A_att, const float* __restrict__ W_att,
               float* __restrict__ T)
{
    int h = blockIdx.y, i = blockIdx.x, j = threadIdx.x;
    const float* A = A_att + (size_t)h * 16384;
    const float* W = W_att + (size_t)h * 16384;
    float s = 0.f;
    for (int k = 0; k < 128; ++k) s = fmaf(A[i * 128 + k], W[j * 128 + k], s);
    T[(size_t)h * 16384 + i * 128 + j] = s;
}

// ---- Mt[n][k] = (sum_h W_h@T_h)[k][n] bf16 ----------------------------------
__global__ __launch_bounds__(128)
void att_fold2(const float* __restrict__ W_att, const float* __restrict__ T,
               short* __restrict__ Mt)
{
    int i = blockIdx.x, j = threadIdx.x;
    float s = 0.f;
    for (int h = 0; h < HEADS; ++h) {
        const float* W = W_att + (size_t)h * 16384 + i * 128;
        const float* Th = T + (size_t)h * 16384;
        for (int k = 0; k < 128; ++k) s = fmaf(W[k], Th[k * 128 + j], s);
    }
    Mt[(size_t)j * 128 + i] = f2bf(s);
}

// ---- u = sum W_h(A_h b_h), v = sum (b_h A_h)W_h^T, c0 = sum b_h.(A_h b_h) ---
__global__ __launch_bounds__(128)
void att_fold3(const float* __restrict__ W_att, const float* __restrict__ b_att,
               const float* __restrict__ A_att,
               float* __restrict__ u, float* __restrict__ v, float* __restrict__ c0)
{
    __shared__ float tb[HEADS][128], tv[HEADS][128];
    int t = threadIdx.x;
    for (int h = 0; h < HEADS; ++h) {
        const float* A = A_att + (size_t)h * 16384;
        const float* b = b_att + h * 128;
        float sb = 0.f, sv = 0.f;
        for (int j = 0; j < 128; ++j) {
            sb = fmaf(A[t * 128 + j], b[j], sb);
            sv = fmaf(b[j], A[j * 128 + t], sv);
        }
        tb[h][t] = sb; tv[h][t] = sv;
    }
    __syncthreads();
    float su = 0.f, sv2 = 0.f;
    for (int h = 0; h < HEADS; ++h) {
        const float* W = W_att + (size_t)h * 16384 + t * 128;
        for (int k = 0; k < 128; ++k) {
            su = fmaf(W[k], tb[h][k], su);
            sv2 = fmaf(W[k], tv[h][k], sv2);
        }
    }
    u[t] = su; v[t] = sv2;
    if (t == 0) {
        float c = 0.f;
        for (int h = 0; h < HEADS; ++h)
            for (int k = 0; k < 128; ++k) c += b_att[h * 128 + k] * tb[h][k];
        *c0 = c;
    }
}

// ---- edge attention: sigmoid(0.25*(q[r].x[c] + a[r] + b[c] + c0)) -----------
__global__ __launch_bounds__(256)
void edge_att(const short* __restrict__ q, const short* __restrict__ xb,
              const int* __restrict__ row, const int* __restrict__ col,
              const float* __restrict__ a, const float* __restrict__ b,
              const float* __restrict__ c0, float* __restrict__ att, int E)
{
    int t = blockIdx.x * 256 + threadIdx.x;
    int e = t >> 4, j = t & 15;
    if (e >= E) return;
    int r = row[e], c = col[e];
    uint4 qa = *(const uint4*)&q[(size_t)r * 128 + j * 8];
    uint4 xa = *(const uint4*)&xb[(size_t)c * 128 + j * 8];
    float p = dot2(qa.x, xa.x) + dot2(qa.y, xa.y) + dot2(qa.z, xa.z) + dot2(qa.w, xa.w);
    p += __shfl_xor(p, 1); p += __shfl_xor(p, 2);
    p += __shfl_xor(p, 4); p += __shfl_xor(p, 8);
    if (j == 0) {
        float s = 0.25f * (p + a[r] + b[c] + *c0);
        att[e] = 1.f / (1.f + expf(-s));
    }
}

// --------- Wf1t[c][r] = W_f1[r][c] bf16 (256x128) ----------------------------
__global__ __launch_bounds__(256)
void wf1_transpose(const float* __restrict__ W, short* __restrict__ Wt)
{
    int r = blockIdx.x;
    int c = threadIdx.x;
    Wt[(size_t)c * 128 + r] = f2bf(W[(size_t)r * 256 + c]);
}

// --------- G1 (64x64) -> G1t bf16; G2 (64x128) -> G2t[128][64] bf16 ----------
__global__ __launch_bounds__(64)
void transpose_g(const float* __restrict__ G1, const float* __restrict__ G2,
                 short* __restrict__ G1t, short* __restrict__ G2t)
{
    int b = blockIdx.x;
    int j = threadIdx.x;
    if (b < 64) {
        G1t[(size_t)j * 64 + b] = f2bf(G1[(size_t)b * 64 + j]);
    } else {
        int n = b - 64;
        G2t[(size_t)n * 64 + j] = f2bf(G2[(size_t)j * 128 + n]);
    }
}

// ---- Wefft[o][k] = (W_f2 @ (W_l0[2j]+W_l0[2j+1]))[k][o] bf16; beff fp32 -----
__global__ __launch_bounds__(64)
void build_weff(const float* __restrict__ W_f2, const float* __restrict__ b_f2,
                const float* __restrict__ W_l0, const float* __restrict__ b_l0,
                short* __restrict__ Wefft, float* __restrict__ beff)
{
    int o = threadIdx.x;
    int k = blockIdx.x;
    if (k < 256) {
        float a = 0.f;
        for (int j = 0; j < 8; ++j) {
            float w = W_l0[(2 * j) * 64 + o] + W_l0[(2 * j + 1) * 64 + o];
            a = fmaf(W_f2[k * 8 + j], w, a);
        }
        Wefft[(size_t)o * 256 + k] = f2bf(a);
    } else {
        float a = b_l0[o];
        for (int j = 0; j < 8; ++j) {
            float w = W_l0[(2 * j) * 64 + o] + W_l0[(2 * j + 1) * 64 + o];
            a = fmaf(b_f2[j], w, a);
        }
        beff[o] = a;
    }
}

// ---- group bounds: gb[g] = first i with batch[i] >= g (batch sorted) --------
__global__ __launch_bounds__(128)
void group_bounds(const int* __restrict__ batch, int N, int* __restrict__ gb)
{
    int g = threadIdx.x;
    if (g > 64) return;
    int lo = 0, hi = N;
    while (lo < hi) {
        int mid = (lo + hi) >> 1;
        if (batch[mid] < g) lo = mid + 1; else hi = mid;
    }
    gb[g] = lo;
}

// ---- contiguous segment sums (64 bf16 cols) using group bounds --------------
// grid: dim3(CHUNKS, 64); block 256 = 4 waves.
__global__ __launch_bounds__(256)
void segsum(const short* __restrict__ v, const int* __restrict__ gb,
            float* __restrict__ sums)
{
    const int g = blockIdx.y;
    const int beg = gb[g], end = gb[g + 1];
    const int len = end - beg;
    const int nch = gridDim.x;
    const int per = (len + nch - 1) / nch;
    const int s = beg + blockIdx.x * per;
    const int e = min(s + per, end);
    if (s >= e) return;          // block-uniform: whole block exits together
    const int lane = threadIdx.x & 63;
    const int wv   = threadIdx.x >> 6;
    const int lq   = lane >> 4;
    const int lr   = lane & 15;
    float4 a = make_float4(0.f, 0.f, 0.f, 0.f);
    for (int i = s + wv * 4 + lq; i < e; i += 16) {
        uint2 d = *(const uint2*)&v[(size_t)i * 64 + lr * 4];
        a.x += bflo(d.x); a.y += bfhi(d.x);
        a.z += bflo(d.y); a.w += bfhi(d.y);
    }
    a.x += __shfl_xor(a.x, 16); a.x += __shfl_xor(a.x, 32);
    a.y += __shfl_xor(a.y, 16); a.y += __shfl_xor(a.y, 32);
    a.z += __shfl_xor(a.z, 16); a.z += __shfl_xor(a.z, 32);
    a.w += __shfl_xor(a.w, 16); a.w += __shfl_xor(a.w, 32);
    __shared__ float red[4][64];
    if (lq == 0) {
        red[wv][lr * 4 + 0] = a.x; red[wv][lr * 4 + 1] = a.y;
        red[wv][lr * 4 + 2] = a.z; red[wv][lr * 4 + 3] = a.w;
    }
    __syncthreads();
    if (threadIdx.x < 64) {
        int j = threadIdx.x;
        float t = red[0][j] + red[1][j] + red[2][j] + red[3][j];
        atomicAdd(&sums[(size_t)g * 64 + j], t);
    }
}

// ---- xm = (sums/cnt) @ L, cnt from gb ---------------------------------------
__global__ void xm_compute(const float* __restrict__ sums, const int* __restrict__ gb,
                           const float* __restrict__ L, float* __restrict__ xm, int Fout)
{
    int g = blockIdx.x;
    int j = threadIdx.x;
    float inv = 1.f / fmaxf((float)(gb[g + 1] - gb[g]), 1.f);
    float a = 0.f;
    for (int k = 0; k < 64; ++k)
        a = fmaf(sums[g * 64 + k] * inv, L[k * Fout + j], a);
    xm[g * Fout + j] = a;
}

// ---- BN partial reduce stage A: gmm rows -> 64 rows -------------------------
__global__ __launch_bounds__(256)
void bn_reduceA(const float* __restrict__ part, int nblk, float* __restrict__ out)
{
    int j = threadIdx.x;
    int b0 = blockIdx.x;   // 0..63
    float a = 0.f;
    for (int b = b0; b < nblk; b += 64) a += part[(size_t)b * 256 + j];
    out[(size_t)b0 * 256 + j] = a;
}

// ---- final BN: reduce 64 partials + compute scale/shift ---------------------
__global__ __launch_bounds__(256)
void bn_final2(const float* __restrict__ part,
               const float* __restrict__ gamma, const float* __restrict__ beta,
               float* __restrict__ scale, float* __restrict__ shift, float invN)
{
    int j = threadIdx.x;
    float a0 = 0.f, a1 = 0.f, a2 = 0.f, a3 = 0.f;
#pragma unroll
    for (int b = 0; b < 64; b += 4) {
        a0 += part[(size_t)(b + 0) * 256 + j];
        a1 += part[(size_t)(b + 1) * 256 + j];
        a2 += part[(size_t)(b + 2) * 256 + j];
        a3 += part[(size_t)(b + 3) * 256 + j];
    }
    float t = (a0 + a1) + (a2 + a3);
    __shared__ float tot[256];
    tot[j] = t;
    __syncthreads();
    if (j < 128) {
        float mu = tot[j] * invN;
        float var = tot[128 + j] * invN - mu * mu;
        float sc = gamma[j] * rsqrtf(var + 1e-5f);
        scale[j] = sc;
        shift[j] = beta[j] - mu * sc;
    }
}

// ---------------- out = x + relu(x0_bf)*scale + shift ------------------------
__global__ __launch_bounds__(256)
void finalize(const float* __restrict__ x, const short* __restrict__ x0b,
              const float* __restrict__ scale, const float* __restrict__ shift,
              float* __restrict__ out, int total4)
{
    int i = blockIdx.x * blockDim.x + threadIdx.x;
    if (i >= total4) return;
    int f0 = (i * 4) & 127;
    uint2 h2 = ((const uint2*)x0b)[i];
    float4 xv = ((const float4*)x)[i];
    float4 sc = *(const float4*)&scale[f0];
    float4 sh = *(const float4*)&shift[f0];
    float4 o;
    o.x = xv.x + fmaxf(bflo(h2.x), 0.f) * sc.x + sh.x;
    o.y = xv.y + fmaxf(bfhi(h2.x), 0.f) * sc.y + sh.y;
    o.z = xv.z + fmaxf(bflo(h2.y), 0.f) * sc.z + sh.z;
    o.w = xv.w + fmaxf(bfhi(h2.y), 0.f) * sc.w + sh.w;
    ((float4*)out)[i] = o;
}

extern "C" void kernel_launch(void* const* d_in, const int* in_sizes, int n_in,
                              void* d_out, int out_size, void* d_ws, size_t ws_size,
                              hipStream_t stream)
{
    const float* x      = (const float*)d_in[0];
    const int*   ei     = (const int*)d_in[1];
    const int*   batch  = (const int*)d_in[2];
    const float* W_f1   = (const float*)d_in[3];
    const float* b_f1   = (const float*)d_in[4];
    const float* W_f2   = (const float*)d_in[5];
    const float* b_f2   = (const float*)d_in[6];
    const float* W_l0   = (const float*)d_in[7];
    const float* b_l0   = (const float*)d_in[8];
    const float* G1     = (const float*)d_in[9];
    const float* b_g1   = (const float*)d_in[10];
    const float* L1     = (const float*)d_in[11];
    const float* G2     = (const float*)d_in[12];
    const float* b_g2   = (const float*)d_in[13];
    const float* L2     = (const float*)d_in[14];
    const float* gam    = (const float*)d_in[15];
    const float* bet    = (const float*)d_in[16];
    const float* W_att  = (const float*)d_in[17];
    const float* b_att  = (const float*)d_in[18];
    const float* A_att  = (const float*)d_in[19];

    const int N = in_sizes[2];
    const int E = in_sizes[1] / 2;
    const int Npad = (N + 127) & ~127;
    const int gmm = Npad / 128;

    char* p = (char*)d_ws;
    auto alloc = [&](size_t bytes) {
        char* r = p;
        p += (bytes + 255) & ~(size_t)255;
        return r;
    };

    short* x_bf   = (short*)alloc((size_t)Npad * 128 * 2);
    short* q_bf   = (short*)alloc((size_t)Npad * 128 * 2);
    short* s0_bf  = (short*)alloc((size_t)Npad * 64 * 2);
    short* s1_bf  = (short*)alloc((size_t)Npad * 64 * 2);
    short* x0_bf  = (short*)alloc((size_t)Npad * 128 * 2);
    float* a_arr  = (float*)alloc((size_t)N * 4);
    float* b_arr  = (float*)alloc((size_t)N * 4);
    float* bnpart = (float*)alloc((size_t)gmm * 256 * 4);
    float* bnredA = (float*)alloc(64 * 256 * 4);
    float* Tbuf   = (float*)alloc((size_t)HEADS * 128 * 128 * 4);
    short* Mt     = (short*)alloc(128 * 128 * 2);
    float* u_v    = (float*)alloc(128 * 4);
    float* v_v    = (float*)alloc(128 * 4);
    float* c0_v   = (float*)alloc(4);
    short* Wf1t   = (short*)alloc(256 * 128 * 2);
    short* Wefft  = (short*)alloc(64 * 256 * 2);
    float* beff   = (float*)alloc(64 * 4);
    short* G1t    = (short*)alloc(64 * 64 * 2);
    short* G2t    = (short*)alloc(128 * 64 * 2);
    int*   gb     = (int*)alloc(65 * 4);
    float* zblk   = (float*)alloc((64 * 64 * 2) * 4);
    float* xm1    = (float*)alloc(64 * 64 * 4);
    float* xm2    = (float*)alloc(64 * 128 * 4);
    float* bscale = (float*)alloc(128 * 4);
    float* bshift = (float*)alloc(128 * 4);

    if ((size_t)(p - (char*)d_ws) > ws_size) return;

    float* sums1 = zblk;
    float* sums2 = zblk + 64 * 64;

    float* out0    = (float*)d_out;
    float* att_out = out0 + (size_t)N * 128;

    hipMemsetAsync(zblk, 0, (64 * 64 * 2) * 4, stream);

    // prologue: group bounds, fold attention, build weights
    group_bounds<<<1, 128, 0, stream>>>(batch, N, gb);
    att_fold1<<<dim3(128, HEADS), 128, 0, stream>>>(A_att, W_att, Tbuf);
    att_fold2<<<128, 128, 0, stream>>>(W_att, Tbuf, Mt);
    att_fold3<<<1, 128, 0, stream>>>(W_att, b_att, A_att, u_v, v_v, c0_v);
    pack_x<<<(Npad * 16 + 255) / 256, 256, 0, stream>>>(x, u_v, v_v, x_bf,
                                                        a_arr, b_arr, N, Npad);
    wf1_transpose<<<128, 256, 0, stream>>>(W_f1, Wf1t);
    build_weff<<<257, 64, 0, stream>>>(W_f2, b_f2, W_l0, b_l0, Wefft, beff);
    transpose_g<<<192, 64, 0, stream>>>(G1, G2, G1t, G2t);

    // q = x @ M
    gemm_rk<128, 128><<<dim3(gmm, 1), 256, 0, stream>>>(
        x_bf, 128, Mt, nullptr, nullptr, 0, nullptr, q_bf, 128,
        nullptr, N, 0);
    edge_att<<<(E * 16 + 255) / 256, 256, 0, stream>>>(
        q_bf, x_bf, ei, ei + E, a_arr, b_arr, c0_v, att_out, E);

    // s0 = relu(relu(x@W_f1+b_f1)@W_eff+b_eff), hidden in LDS only
    filt_s0<<<gmm, 256, 0, stream>>>(x_bf, Wf1t, b_f1, Wefft, beff, s0_bf);

    segsum<<<dim3(8, 64), 256, 0, stream>>>(s0_bf, gb, sums1);
    xm_compute<<<64, 64, 0, stream>>>(sums1, gb, L1, xm1, 64);
    gemm_rk<64, 64><<<dim3(gmm, 1), 256, 0, stream>>>(
        s0_bf, 64, G1t, b_g1, xm1, 64, batch, s1_bf, 64,
        nullptr, N, 1);
    segsum<<<dim3(8, 64), 256, 0, stream>>>(s1_bf, gb, sums2);
    xm_compute<<<64, 128, 0, stream>>>(sums2, gb, L2, xm2, 128);
    gemm_rk<64, 128><<<dim3(gmm, 1), 256, 0, stream>>>(
        s1_bf, 64, G2t, b_g2, xm2, 128, batch, x0_bf, 128,
        bnpart, N, 0);

    bn_reduceA<<<64, 256, 0, stream>>>(bnpart, gmm, bnredA);
    bn_final2<<<1, 256, 0, stream>>>(bnredA, gam, bet, bscale, bshift, 1.f / (float)N);
    finalize<<<((N * 128 / 4) + 255) / 256, 256, 0, stream>>>(x, x0_bf, bscale, bshift,
                                                              out0, N * 128 / 4);
}